// Round 30
// baseline (4059.601 us; speedup 1.0000x reference)
//
#include <hip/hip_runtime.h>

#define LOG2E 1.44269504088896340736f

__device__ __forceinline__ float lrelu(float z) { return fmaxf(z, 0.01f * z); }
__device__ __forceinline__ float sigf(float z) {
    float p = __builtin_amdgcn_exp2f(-LOG2E * z);
    return __builtin_amdgcn_rcpf(1.0f + p);
}

#define WQ(i) __int_as_float(__builtin_amdgcn_readlane(__float_as_int(wreg[(i) >> 6]), (i) & 63))

// ====== PC-v10: pc8 F + X batched over 2-step windows (4-deep hbuf ring) ====
// R29: stagger regressed; lockstep phase-shuffling dead. New lever: x_t are
// independent across t -> X reads each weight ONCE per 2-step window and
// applies it to 2 steps x 2 points (4 outputs): X broadcast VALU and X LDS
// traffic both halve. Window split across 2 iterations (A: rows 0..24 at odd
// s; B: rows 25..49 + layer3 + stores at even s), so X per-iteration ~6.5K
// cyc < F ~7.9K (F binds). hbuf[4] ring: F writes t&3; X reads (t-2)&3,
// (t-1)&3 at iter t; overwrite at t+2 — barrier-safe. xacc[2][2][20]=80 VGPR
// live across one barrier, static indices. X pin dropped (rows 39..45 via
// uniform L2 at half frequency); F identical to pc8 (wv[140] pin).
__global__ void __launch_bounds__(256, 1)
pc10_kernel(const float* __restrict__ w,
            const float* __restrict__ Wh1, const float* __restrict__ bh1,
            const float* __restrict__ Wh2, const float* __restrict__ bh2,
            const float* __restrict__ Wh3, const float* __restrict__ bh3,
            const float* __restrict__ Wx1, const float* __restrict__ bx1,
            const float* __restrict__ Wx2, const float* __restrict__ bx2,
            const float* __restrict__ Wx3, const float* __restrict__ bx3,
            float2* __restrict__ out, int B, int T)
{
    __shared__ float4 sW2h[185];       // Wh2 rows 0..36
    __shared__ float4 sW2x[195];       // Wx2 rows 0..38
    __shared__ float2 hbuf[4][256];    // 4-deep ring

    {
        float* a = (float*)sW2h;
        for (int i = threadIdx.x; i < 740; i += 256) a[i] = Wh2[i];
        float* b = (float*)sW2x;
        for (int i = threadIdx.x; i < 780; i += 256) b[i] = Wx2[i];
    }

    const int wid  = threadIdx.x >> 6;     // 0..3
    const int lane = threadIdx.x & 63;
    const bool is_f = (wid < 2);

    float wreg[6];
    float wv[140];   // F-only pin (pc8 mechanism)
    if (is_f) {
#pragma unroll
        for (int r = 0; r < 6; ++r) {
            const int idx = r * 64 + lane;
            float v = 0.f;
            if      (idx < 100) v = Wh1[idx];
            else if (idx < 150) v = bh1[idx - 100];
            else if (idx < 270) v = Wh2[880 + (idx - 150)];   // rows 44..49
            else if (idx < 290) v = bh2[idx - 270];
            else if (idx < 330) v = Wh3[idx - 290];
            else if (idx < 332) v = bh3[idx - 330];
            wreg[r] = v;
        }
#pragma unroll
        for (int i = 0; i < 140; ++i) {        // pin Wh2 rows 37..43
            wv[i] = Wh2[740 + i];
            asm volatile("" : "+v"(wv[i]));
        }
    } else {
#pragma unroll
        for (int r = 0; r < 6; ++r) {
            const int idx = r * 64 + lane;
            float v = 0.f;
            if      (idx < 100) v = Wx1[idx];
            else if (idx < 150) v = bx1[idx - 100];
            else if (idx < 230) v = Wx2[920 + (idx - 150)];   // rows 46..49
            else if (idx < 250) v = bx2[idx - 230];
            else if (idx < 290) v = Wx3[idx - 250];
            else if (idx < 292) v = bx3[idx - 290];
            wreg[r] = v;
        }
    }
    __syncthreads();

    const int lw = is_f ? wid : (wid - 2);
    const int lpA = lw * 128 + lane;
    const int lpB = lpA + 64;
    const int pA  = blockIdx.x * 256 + lpA;
    const int pB  = blockIdx.x * 256 + lpB;

    float hA0 = 0.f, hA1 = 0.f, hB0 = 0.f, hB1 = 0.f;
    if (is_f) {
        hA0 = w[2 * pA]; hA1 = w[2 * pA + 1];
        hB0 = w[2 * pB]; hB1 = w[2 * pB + 1];
    }
    float2* __restrict__ orowA = out + (size_t)pA * (size_t)T;
    float2* __restrict__ orowB = out + (size_t)pB * (size_t)T;

    // X persistent window state (static indices only)
    float2 xh[2][2];         // [pt][st]
    float  xacc[2][2][20];   // [pt][st][c]
    const float* __restrict__ gWx2 = Wx2 + 780;   // rows 39..45 (uniform L2)

    for (int t = 0; t <= T + 1; ++t) {
        if (is_f) {
            if (t < T) {
                // ===== F: identical to pc8 =====
                float a1A[50], a1B[50];
#pragma unroll
                for (int j = 0; j < 50; ++j) {
                    const float s0 = WQ(j), s1 = WQ(50 + j), sb = WQ(100 + j);
                    a1A[j] = lrelu(fmaf(hA0, s0, fmaf(hA1, s1, sb)));
                    a1B[j] = lrelu(fmaf(hB0, s0, fmaf(hB1, s1, sb)));
                }
                float accA[20], accB[20];
#pragma unroll
                for (int c = 0; c < 20; ++c) {
                    const float bv = WQ(270 + c);
                    accA[c] = bv; accB[c] = bv;
                }
#pragma unroll
                for (int k = 0; k < 37; ++k) {          // rows 0..36 via LDS
                    const float akA = a1A[k], akB = a1B[k];
#pragma unroll
                    for (int c = 0; c < 5; ++c) {
                        const float4 v = sW2h[k * 5 + c];
                        accA[4*c+0] = fmaf(akA, v.x, accA[4*c+0]);
                        accA[4*c+1] = fmaf(akA, v.y, accA[4*c+1]);
                        accA[4*c+2] = fmaf(akA, v.z, accA[4*c+2]);
                        accA[4*c+3] = fmaf(akA, v.w, accA[4*c+3]);
                        accB[4*c+0] = fmaf(akB, v.x, accB[4*c+0]);
                        accB[4*c+1] = fmaf(akB, v.y, accB[4*c+1]);
                        accB[4*c+2] = fmaf(akB, v.z, accB[4*c+2]);
                        accB[4*c+3] = fmaf(akB, v.w, accB[4*c+3]);
                    }
                }
#pragma unroll
                for (int k = 37; k < 44; ++k) {         // rows 37..43 via pin
                    const float akA = a1A[k], akB = a1B[k];
#pragma unroll
                    for (int c = 0; c < 20; ++c) {
                        const float wvv = wv[(k - 37) * 20 + c];
                        accA[c] = fmaf(akA, wvv, accA[c]);
                        accB[c] = fmaf(akB, wvv, accB[c]);
                    }
                }
#pragma unroll
                for (int k = 44; k < 50; ++k) {         // rows 44..49 via RL
                    const float akA = a1A[k], akB = a1B[k];
#pragma unroll
                    for (int c = 0; c < 20; ++c) {
                        const float wvv = WQ(150 + (k - 44) * 20 + c);
                        accA[c] = fmaf(akA, wvv, accA[c]);
                        accB[c] = fmaf(akB, wvv, accB[c]);
                    }
                }
                float zA0 = WQ(330), zA1 = WQ(331);
                float zB0 = zA0, zB1 = zA1;
#pragma unroll
                for (int k = 0; k < 20; ++k) {
                    const float wx = WQ(290 + 2 * k), wy = WQ(291 + 2 * k);
                    const float eA = lrelu(accA[k]), eB = lrelu(accB[k]);
                    zA0 = fmaf(eA, wx, zA0); zA1 = fmaf(eA, wy, zA1);
                    zB0 = fmaf(eB, wx, zB0); zB1 = fmaf(eB, wy, zB1);
                }
                hA0 = lrelu(zA0); hA1 = lrelu(zA1);
                hB0 = lrelu(zB0); hB1 = lrelu(zB1);

                hbuf[t & 3][lpA] = make_float2(hA0, hA1);
                hbuf[t & 3][lpB] = make_float2(hB0, hB1);
            }
        } else {
            const int s = t - 1;
            if (s >= 1 && (s & 1) == 1) {
                // ===== X chunk A: start window (s-1, s); rows 0..24 =====
                xh[0][0] = hbuf[(s - 1) & 3][lpA];
                xh[0][1] = hbuf[s & 3][lpA];
                xh[1][0] = hbuf[(s - 1) & 3][lpB];
                xh[1][1] = hbuf[s & 3][lpB];
#pragma unroll
                for (int c = 0; c < 20; ++c) {
                    const float bv = WQ(230 + c);
                    xacc[0][0][c] = bv; xacc[0][1][c] = bv;
                    xacc[1][0][c] = bv; xacc[1][1][c] = bv;
                }
#pragma unroll
                for (int k = 0; k < 25; ++k) {
                    const float s0 = WQ(k), s1 = WQ(50 + k), sb = WQ(100 + k);
                    float xk[2][2];
#pragma unroll
                    for (int p = 0; p < 2; ++p)
#pragma unroll
                        for (int q = 0; q < 2; ++q)
                            xk[p][q] = sigf(fmaf(xh[p][q].x, s0, fmaf(xh[p][q].y, s1, sb)));
#pragma unroll
                    for (int c4 = 0; c4 < 5; ++c4) {
                        const float4 v = sW2x[k * 5 + c4];
#pragma unroll
                        for (int p = 0; p < 2; ++p)
#pragma unroll
                            for (int q = 0; q < 2; ++q) {
                                xacc[p][q][4*c4+0] = fmaf(xk[p][q], v.x, xacc[p][q][4*c4+0]);
                                xacc[p][q][4*c4+1] = fmaf(xk[p][q], v.y, xacc[p][q][4*c4+1]);
                                xacc[p][q][4*c4+2] = fmaf(xk[p][q], v.z, xacc[p][q][4*c4+2]);
                                xacc[p][q][4*c4+3] = fmaf(xk[p][q], v.w, xacc[p][q][4*c4+3]);
                            }
                    }
                }
            } else if (s >= 2 && (s & 1) == 0) {
                // ===== X chunk B: finish window (s-2, s-1); rows 25..49 =====
#pragma unroll
                for (int k = 25; k < 50; ++k) {
                    const float s0 = WQ(k), s1 = WQ(50 + k), sb = WQ(100 + k);
                    float xk[2][2];
#pragma unroll
                    for (int p = 0; p < 2; ++p)
#pragma unroll
                        for (int q = 0; q < 2; ++q)
                            xk[p][q] = sigf(fmaf(xh[p][q].x, s0, fmaf(xh[p][q].y, s1, sb)));
                    if (k < 39) {                        // rows 25..38 via LDS
#pragma unroll
                        for (int c4 = 0; c4 < 5; ++c4) {
                            const float4 v = sW2x[k * 5 + c4];
#pragma unroll
                            for (int p = 0; p < 2; ++p)
#pragma unroll
                                for (int q = 0; q < 2; ++q) {
                                    xacc[p][q][4*c4+0] = fmaf(xk[p][q], v.x, xacc[p][q][4*c4+0]);
                                    xacc[p][q][4*c4+1] = fmaf(xk[p][q], v.y, xacc[p][q][4*c4+1]);
                                    xacc[p][q][4*c4+2] = fmaf(xk[p][q], v.z, xacc[p][q][4*c4+2]);
                                    xacc[p][q][4*c4+3] = fmaf(xk[p][q], v.w, xacc[p][q][4*c4+3]);
                                }
                        }
                    } else if (k < 46) {                 // rows 39..45 via L2
#pragma unroll
                        for (int c = 0; c < 20; ++c) {
                            const float wvv = gWx2[(k - 39) * 20 + c];
#pragma unroll
                            for (int p = 0; p < 2; ++p)
#pragma unroll
                                for (int q = 0; q < 2; ++q)
                                    xacc[p][q][c] = fmaf(xk[p][q], wvv, xacc[p][q][c]);
                        }
                    } else {                             // rows 46..49 via RL
#pragma unroll
                        for (int c = 0; c < 20; ++c) {
                            const float wvv = WQ(150 + (k - 46) * 20 + c);
#pragma unroll
                            for (int p = 0; p < 2; ++p)
#pragma unroll
                                for (int q = 0; q < 2; ++q)
                                    xacc[p][q][c] = fmaf(xk[p][q], wvv, xacc[p][q][c]);
                        }
                    }
                }
                // layer 3 + stores, broadcasts shared across 4 outputs
                float z0[2][2], z1[2][2];
#pragma unroll
                for (int p = 0; p < 2; ++p)
#pragma unroll
                    for (int q = 0; q < 2; ++q) { z0[p][q] = WQ(290); z1[p][q] = WQ(291); }
#pragma unroll
                for (int k = 0; k < 20; ++k) {
                    const float wx = WQ(250 + 2 * k), wy = WQ(251 + 2 * k);
#pragma unroll
                    for (int p = 0; p < 2; ++p)
#pragma unroll
                        for (int q = 0; q < 2; ++q) {
                            const float e = sigf(xacc[p][q][k]);
                            z0[p][q] = fmaf(e, wx, z0[p][q]);
                            z1[p][q] = fmaf(e, wy, z1[p][q]);
                        }
                }
                orowA[s - 2] = make_float2(sigf(z0[0][0]), sigf(z1[0][0]));
                orowA[s - 1] = make_float2(sigf(z0[0][1]), sigf(z1[0][1]));
                orowB[s - 2] = make_float2(sigf(z0[1][0]), sigf(z1[1][0]));
                orowB[s - 1] = make_float2(sigf(z0[1][1]), sigf(z1[1][1]));
            }
        }
        __syncthreads();   // ring-slot ordering (see header comment)
    }
}

extern "C" void kernel_launch(void* const* d_in, const int* in_sizes, int n_in,
                              void* d_out, int out_size, void* d_ws, size_t ws_size,
                              hipStream_t stream)
{
    const float* w   = (const float*)d_in[0];
    const float* Wh1 = (const float*)d_in[1];
    const float* bh1 = (const float*)d_in[2];
    const float* Wh2 = (const float*)d_in[3];
    const float* bh2 = (const float*)d_in[4];
    const float* Wh3 = (const float*)d_in[5];
    const float* bh3 = (const float*)d_in[6];
    const float* Wx1 = (const float*)d_in[7];
    const float* bx1 = (const float*)d_in[8];
    const float* Wx2 = (const float*)d_in[9];
    const float* bx2 = (const float*)d_in[10];
    const float* Wx3 = (const float*)d_in[11];
    const float* bx3 = (const float*)d_in[12];

    const int B = in_sizes[0] / 2;        // 65536 (divisible by 256)
    const int T = out_size / (B * 2);     // 512 (even)

    pc10_kernel<<<B / 256, 256, 0, stream>>>(
        w, Wh1, bh1, Wh2, bh2, Wh3, bh3,
        Wx1, bx1, Wx2, bx2, Wx3, bx3,
        (float2*)d_out, B, T);
}